// Round 1
// baseline (16825.923 us; speedup 1.0000x reference)
//
#include <hip/hip_runtime.h>
#include <cstdint>

#define TT 256
#define BB 8
#define NE 64
#define HH 512
#define VOCAB 32000
#define G4 2048
#define RS 32064          // out0 row stride (V + NE)
#define MROWS 2048        // B*T
#define NWG 128
#define SCALE 0.044194173824159216f  // 1/sqrt(512)

typedef _Float16 h2 __attribute__((ext_vector_type(2)));
typedef _Float16 h8 __attribute__((ext_vector_type(8)));
typedef float f4 __attribute__((ext_vector_type(4)));

__device__ inline float sigf(float x){ return 1.f/(1.f+__expf(-x)); }

// ---------------- casts (f32 -> f16, hi or lo residual) ----------------
__global__ __launch_bounds__(256) void cast_k(const float* __restrict__ src, _Float16* __restrict__ dst,
    int total, int src_ld, int src_off, int dst_ld, int dst_off, int cshift, int lo)
{
  int i = blockIdx.x*256 + threadIdx.x;
  if (i >= total) return;
  int c = i & ((1<<cshift)-1);
  int r = i >> cshift;
  float x = src[(long)r*src_ld + src_off + c];
  _Float16 h = (_Float16)x;
  if (lo) h = (_Float16)(x - (float)h);
  dst[(long)r*dst_ld + dst_off + c] = h;
}

__global__ __launch_bounds__(256) void embgather_k(const float* __restrict__ emb,
    const int* __restrict__ outp, _Float16* __restrict__ dst)
{
  int i = blockIdx.x*256 + threadIdx.x;   // < 2048*512, rows m = t*8+b
  int k = i & 511; int m = i >> 9;
  int t = m >> 3, b = m & 7;
  int tok = outp[b*TT + t];
  dst[i] = (_Float16)emb[(long)tok*HH + k];
}

__global__ __launch_bounds__(256) void prep_k(const float* __restrict__ b_ih, const float* __restrict__ b_hh,
    const float* __restrict__ ents, float* bsum, float* hxA, float* aA, int* bar)
{
  int i = blockIdx.x*256 + threadIdx.x;   // grid 16 -> 4096 threads
  if (i < G4) bsum[i] = b_ih[i] + b_hh[i];
  if (i < BB*HH) {
    int b = i >> 9, j = i & 511;
    float s = 0.f;
    for (int n = 0; n < NE; n++) s += ents[(size_t)((b<<6)+n)*HH + j];
    hxA[i] = s * (1.0f/NE);   // cx0 = hx0 = mean over ALL NE entities
    aA[i]  = 0.f;
  }
  if (i < 2) bar[i] = 0;
}

// ---------------- f16 MFMA GEMM: C[M,N](f32) = A[M,K] * B[N,K]^T (+bias) ----------------
// All of M,N,K divisible by 128/32. 128x128 tile, 4 waves each 64x64.
__global__ __launch_bounds__(256) void gemm_k(const _Float16* __restrict__ A, const _Float16* __restrict__ Bm,
    float* __restrict__ C, const float* __restrict__ bias,
    int M, int N, int K, int ldc, int accum)
{
  __shared__ __align__(16) _Float16 At[128][40];
  __shared__ __align__(16) _Float16 Bt[128][40];
  int tid = threadIdx.x;
  int n0 = blockIdx.x * 128, m0 = blockIdx.y * 128;
  int wave = tid >> 6, lane = tid & 63;
  int mw = (wave & 1) << 6, nw = (wave >> 1) << 6;
  int lr = tid >> 2, lc = (tid & 3) << 3;
  const _Float16* Ap0 = A + (long)(m0 + lr)*K + lc;
  const _Float16* Ap1 = Ap0 + (long)64*K;
  const _Float16* Bp0 = Bm + (long)(n0 + lr)*K + lc;
  const _Float16* Bp1 = Bp0 + (long)64*K;
  f4 acc[4][4] = {};
  int rr = lane & 15, kq = (lane >> 4) << 3;
  for (int kt = 0; kt < K; kt += 32) {
    h8 av0 = *(const h8*)(Ap0 + kt);
    h8 av1 = *(const h8*)(Ap1 + kt);
    h8 bv0 = *(const h8*)(Bp0 + kt);
    h8 bv1 = *(const h8*)(Bp1 + kt);
    __syncthreads();
    *(h8*)&At[lr][lc]    = av0;
    *(h8*)&At[64+lr][lc] = av1;
    *(h8*)&Bt[lr][lc]    = bv0;
    *(h8*)&Bt[64+lr][lc] = bv1;
    __syncthreads();
    h8 af[4], bf[4];
    #pragma unroll
    for (int mt=0;mt<4;mt++) af[mt] = *(const h8*)&At[mw + mt*16 + rr][kq];
    #pragma unroll
    for (int nt=0;nt<4;nt++) bf[nt] = *(const h8*)&Bt[nw + nt*16 + rr][kq];
    #pragma unroll
    for (int mt=0;mt<4;mt++)
      #pragma unroll
      for (int nt=0;nt<4;nt++)
        acc[mt][nt] = __builtin_amdgcn_mfma_f32_16x16x32_f16(af[mt], bf[nt], acc[mt][nt], 0, 0, 0);
  }
  // C/D layout: col=lane&15, row=(lane>>4)*4+reg  (dtype-independent on gfx950)
  int cc = lane & 15, rq = (lane >> 4) << 2;
  #pragma unroll
  for (int nt=0;nt<4;nt++) {
    int col = n0 + nw + nt*16 + cc;
    float bv = bias ? bias[col] : 0.f;
    #pragma unroll
    for (int mt=0;mt<4;mt++) {
      int row0 = m0 + mw + mt*16 + rq;
      #pragma unroll
      for (int r=0;r<4;r++) {
        long idx = (long)(row0 + r)*ldc + col;
        float v = acc[mt][nt][r] + bv;
        if (accum) C[idx] += v; else C[idx] = v;
      }
    }
  }
}

// ---------------- persistent LSTM+MHA scan ----------------
__device__ inline void gbar(int* bar) {
  __syncthreads();
  if (threadIdx.x == 0) {
    int g = __hip_atomic_load(bar+1, __ATOMIC_RELAXED, __HIP_MEMORY_SCOPE_AGENT);
    int old = __hip_atomic_fetch_add(bar, 1, __ATOMIC_ACQ_REL, __HIP_MEMORY_SCOPE_AGENT);
    if (old == NWG-1) {
      __hip_atomic_store(bar, 0, __ATOMIC_RELAXED, __HIP_MEMORY_SCOPE_AGENT);
      __hip_atomic_fetch_add(bar+1, 1, __ATOMIC_RELEASE, __HIP_MEMORY_SCOPE_AGENT);
    } else {
      while (__hip_atomic_load(bar+1, __ATOMIC_ACQUIRE, __HIP_MEMORY_SCOPE_AGENT) == g)
        __builtin_amdgcn_s_sleep(2);
    }
  }
  __syncthreads();
}

struct PB { float hxl[512]; float q[128]; float pr[256]; float sc2[64]; };

__global__ __launch_bounds__(256, 1) void lstm_k(
    const float* __restrict__ gates_pre, const _Float16* __restrict__ Wc,
    const _Float16* __restrict__ Wq, const float* __restrict__ Kb, const float* __restrict__ Vb,
    const int* __restrict__ entlens,
    float* hxA, float* hxB, float* aA, float* aB,
    _Float16* l_h, _Float16* l_lo, int* bar)
{
  __shared__ __align__(16) _Float16 wA[16][1032];   // 16 gate rows x 1024 (a|hx) weights
  __shared__ __align__(16) union {
    _Float16 act[8][1032];      // [b][a(512)|hx(512)]
    float red[256][16];
    PB pb;
  } u;
  __shared__ float cxs[32];     // persistent cell state: [b(8)][jj(4)]
  __shared__ float fin[8][16];

  int wg = blockIdx.x, tid = threadIdx.x;

  // one-time: weights -> LDS; cx init
  for (int i = tid; i < 16*1024; i += 256) {
    int rl = i >> 10, d = i & 1023;
    int gr = (rl >> 2)*512 + (wg << 2) + (rl & 3);   // gate*512 + j
    wA[rl][d] = Wc[(long)gr*1024 + d];
  }
  if (tid < 32) cxs[tid] = hxA[(tid>>2)*512 + (wg<<2) + (tid&3)];
  int el = entlens[(wg < 32) ? (wg >> 2) : 0];

  int tile = tid >> 5, ds = tid & 31;
  int bt4 = (tile >> 2) << 2;
  int rt4 = (tile & 3) << 2;
  int rb = tid >> 4, rrl = tid & 15;                  // reducer mapping (tid<128)
  int rtl = ((rb >> 2) << 2) + (rrl >> 2);
  int rai = ((rb & 3) << 2) + (rrl & 3);
  long gp_col = (long)((rrl >> 2)*512 + (wg << 2) + (rrl & 3));
  __syncthreads();

  for (int t = 0; t < TT; t++) {
    const float* hx_old = (t & 1) ? hxB : hxA;
    float*       hx_new = (t & 1) ? hxA : hxB;
    const float* a_old  = (t & 1) ? aB : aA;
    float*       a_new  = (t & 1) ? aA : aB;

    float gp = 0.f;
    if (tid < 128) gp = gates_pre[(long)((t<<3) + rb)*2048 + gp_col];

    // stage activations [a_old | hx_old] -> LDS f16
    for (int i = tid; i < 8192; i += 256) {
      int b = i >> 10, d = i & 1023;
      float v = (d < 512) ? a_old[(b<<9) + d] : hx_old[(b<<9) + d - 512];
      u.act[b][d] = (_Float16)v;
    }
    __syncthreads();

    // gates accumulation: thread tile 4b x 4rows, 32-wide d-split, f16 dot2
    float acc[4][4] = {};
    #pragma unroll
    for (int c=0;c<4;c++) {
      int d0 = ((c<<5) + ds) << 3;
      union { h8 v; h2 p[4]; } av[4], wv[4];
      #pragma unroll
      for (int i=0;i<4;i++) av[i].v = *(const h8*)&u.act[bt4+i][d0];
      #pragma unroll
      for (int i=0;i<4;i++) wv[i].v = *(const h8*)&wA[rt4+i][d0];
      #pragma unroll
      for (int bi=0;bi<4;bi++)
        #pragma unroll
        for (int ri=0;ri<4;ri++)
          #pragma unroll
          for (int p=0;p<4;p++)
            acc[bi][ri] = __builtin_amdgcn_fdot2(av[bi].p[p], wv[ri].p[p], acc[bi][ri], false);
    }
    __syncthreads();
    #pragma unroll
    for (int bi=0;bi<4;bi++)
      #pragma unroll
      for (int ri=0;ri<4;ri++)
        u.red[tid][(bi<<2)+ri] = acc[bi][ri];
    __syncthreads();
    if (tid < 128) {
      float s = gp;
      #pragma unroll 8
      for (int k=0;k<32;k++) s += u.red[(rtl<<5)+k][rai];
      fin[rb][rrl] = s;
    }
    __syncthreads();
    if (tid < 32) {                    // LSTM cell for 8b x 4j
      int b = tid >> 2, jj = tid & 3;
      float gi = fin[b][jj], gf = fin[b][4+jj], gg = fin[b][8+jj], go = fin[b][12+jj];
      float c_ = sigf(gf)*cxs[tid] + sigf(gi)*tanhf(gg);
      cxs[tid] = c_;
      float h = sigf(go)*tanhf(c_);
      int j = (wg<<2) + jj;
      hx_new[(b<<9) + j] = h;
      _Float16 hh = (_Float16)h;
      long li = ((long)((b<<8) + t)) << 10;
      l_h[li + j]  = hh;
      l_lo[li + j] = (_Float16)(h - (float)hh);
    }
    gbar(bar);

    // attention: WG w<32 owns (b = w>>2, head = w&3)
    if (wg < 32) {
      int b = wg >> 2, hid = wg & 3;
      for (int i = tid; i < 512; i += 256) u.pb.hxl[i] = hx_new[(b<<9) + i];
      __syncthreads();
      {
        int qd = tid >> 1, hf = tid & 1;
        const _Float16* wq = Wq + (long)(hid*128 + qd)*512 + (hf<<8);
        const float* hp = u.pb.hxl + (hf<<8);
        float s = 0.f;
        for (int k=0;k<256;k+=8) {
          h8 wv8 = *(const h8*)(wq + k);
          #pragma unroll
          for (int j=0;j<8;j++) s += (float)wv8[j] * hp[k+j];
        }
        u.pb.pr[tid] = s;
      }
      __syncthreads();
      if (tid < 128) u.pb.q[tid] = u.pb.pr[tid<<1] + u.pb.pr[(tid<<1)+1];
      __syncthreads();
      if (tid < 64) {
        const float* kp = Kb + (long)((b<<6)+tid)*512 + hid*128;
        float s = 0.f;
        #pragma unroll 4
        for (int d=0;d<128;d+=4)
          s += u.pb.q[d]*kp[d] + u.pb.q[d+1]*kp[d+1] + u.pb.q[d+2]*kp[d+2] + u.pb.q[d+3]*kp[d+3];
        s *= SCALE;
        if (tid > el) s = -1e30f;
        float mx = s;
        #pragma unroll
        for (int off=32; off>0; off>>=1) mx = fmaxf(mx, __shfl_xor(mx, off));
        float e = __expf(s - mx);
        float sum = e;
        #pragma unroll
        for (int off=32; off>0; off>>=1) sum += __shfl_xor(sum, off);
        u.pb.sc2[tid] = e / sum;
      }
      __syncthreads();
      if (tid < 128) {
        const float* vp = Vb + ((long)(b<<6))*512 + hid*128 + tid;
        float s = 0.f;
        for (int n=0;n<NE;n++) s += u.pb.sc2[n] * vp[(long)n*512];
        a_new[(b<<9) + hid*128 + tid] = s;
        _Float16 hh = (_Float16)s;
        long li = (((long)((b<<8) + t)) << 10) + 512 + hid*128 + tid;
        l_h[li]  = hh;
        l_lo[li] = (_Float16)(s - (float)hh);
      }
    }
    gbar(bar);
  }
}

// ---------------- online softmax stats over V + sigmoid switch gate ----------------
__global__ __launch_bounds__(256) void stats_k(const float* __restrict__ out0,
    const _Float16* __restrict__ l_h, const float* __restrict__ swW, const float* __restrict__ swb,
    float* rowmax, float* rowsum, float* sgate)
{
  int m = blockIdx.x, tid = threadIdx.x;
  const float* row = out0 + (long)m*RS;
  float mx = -1e30f, sm = 0.f;
  for (int c = tid; c < VOCAB; c += 256) {
    float x = row[c];
    float nm = fmaxf(mx, x);
    sm = sm*__expf(mx-nm) + __expf(x-nm);
    mx = nm;
  }
  float sd = 0.f;
  const _Float16* lr_ = l_h + ((long)m << 10);
  for (int k = tid; k < 1024; k += 256) sd += (float)lr_[k] * swW[k];
  #pragma unroll
  for (int off=32; off>0; off>>=1) {
    float omx = __shfl_xor(mx, off), osm = __shfl_xor(sm, off);
    float nm = fmaxf(mx, omx);
    sm = sm*__expf(mx-nm) + osm*__expf(omx-nm);
    mx = nm;
    sd += __shfl_xor(sd, off);
  }
  __shared__ float smx[4], ssm[4], ssd[4];
  int wv = tid >> 6;
  if ((tid & 63) == 0) { smx[wv]=mx; ssm[wv]=sm; ssd[wv]=sd; }
  __syncthreads();
  if (tid == 0) {
    float M = smx[0], S = ssm[0], D = ssd[0];
    for (int w2=1;w2<4;w2++) {
      float nm = fmaxf(M, smx[w2]);
      S = S*__expf(M-nm) + ssm[w2]*__expf(smx[w2]-nm);
      M = nm; D += ssd[w2];
    }
    rowmax[m] = M; rowsum[m] = S;
    sgate[m] = 1.f/(1.f + __expf(-(D + swb[0])));
  }
}

// ---------------- finalize: log(softmax*s + 1e-6) over V, pointer softmax z over NE ----------------
__global__ __launch_bounds__(256) void fin_k(float* __restrict__ out,
    const float* __restrict__ dec, const float* __restrict__ ents, const int* __restrict__ entlens,
    const float* __restrict__ rowmax, const float* __restrict__ rowsum, const float* __restrict__ sgate)
{
  int m = blockIdx.x, tid = threadIdx.x;
  int b = m >> 8;
  __shared__ float dl[512];
  for (int i = tid; i < 512; i += 256) dl[i] = dec[((long)m<<9) + i];
  __syncthreads();
  float s = sgate[m];
  if (tid < 64) {
    int n = tid;
    const float* ep = ents + (((long)((b<<6)+n)) << 9);
    float uq = 0.f;
    for (int k=0;k<512;k+=4)
      uq += dl[k]*ep[k] + dl[k+1]*ep[k+1] + dl[k+2]*ep[k+2] + dl[k+3]*ep[k+3];
    if (n > entlens[b]) uq = -1e30f;
    float mx = uq;
    #pragma unroll
    for (int off=32; off>0; off>>=1) mx = fmaxf(mx, __shfl_xor(mx, off));
    float e = __expf(uq - mx);
    float sum = e;
    #pragma unroll
    for (int off=32; off>0; off>>=1) sum += __shfl_xor(sum, off);
    float z = (e/sum) * (1.f - s);
    out[(long)m*RS + VOCAB + n] = __logf(z + 1e-6f);
    out[(long)MROWS*RS + ((long)m<<6) + n] = z;     // output 1
  }
  float mx = rowmax[m], inv = 1.f/rowsum[m];
  for (int c = tid; c < VOCAB; c += 256) {
    long idx = (long)m*RS + c;
    float x = out[idx];
    out[idx] = __logf(__expf(x - mx)*inv*s + 1e-6f);
  }
}

// ---------------- launch ----------------
extern "C" void kernel_launch(void* const* d_in, const int* in_sizes, int n_in,
                              void* d_out, int out_size, void* d_ws, size_t ws_size,
                              hipStream_t stream)
{
  const int*   outp    = (const int*)d_in[0];
  const float* ents    = (const float*)d_in[1];
  const int*   entlens = (const int*)d_in[2];
  const float* emb     = (const float*)d_in[3];
  const float* W_ih    = (const float*)d_in[4];
  const float* W_hh    = (const float*)d_in[5];
  const float* b_ih    = (const float*)d_in[6];
  const float* b_hh    = (const float*)d_in[7];
  const float* Wq      = (const float*)d_in[8];
  const float* Wk      = (const float*)d_in[9];
  const float* Wv      = (const float*)d_in[10];
  const float* out_W   = (const float*)d_in[11];
  const float* out_b   = (const float*)d_in[12];
  const float* sw_W    = (const float*)d_in[13];
  const float* sw_b    = (const float*)d_in[14];
  const float* mattn_W = (const float*)d_in[15];
  const float* mattn_b = (const float*)d_in[16];
  float* out = (float*)d_out;
  (void)in_sizes; (void)n_in; (void)out_size; (void)ws_size;

  char* w = (char*)d_ws;
  size_t off = 0;
  auto alloc = [&](size_t bytes) -> char* {
    char* p = w + off; off += bytes; off = (off + 255) & ~(size_t)255; return p;
  };
  // ~108 MB total workspace
  _Float16* outW_h = (_Float16*)alloc((size_t)VOCAB*1024*2);
  _Float16* l_h    = (_Float16*)alloc((size_t)MROWS*1024*2);
  _Float16* l_lo   = (_Float16*)alloc((size_t)MROWS*1024*2);
  float*    gpre   = (float*)alloc((size_t)MROWS*2048*4);
  _Float16* Wc_h   = (_Float16*)alloc((size_t)2048*1024*2);
  _Float16* Wihk_h = (_Float16*)alloc((size_t)2048*512*2);
  _Float16* emb_h  = (_Float16*)alloc((size_t)2048*512*2);
  _Float16* ents_h = (_Float16*)alloc((size_t)512*512*2);
  _Float16* Wk_h   = (_Float16*)alloc((size_t)512*512*2);
  _Float16* Wv_h   = (_Float16*)alloc((size_t)512*512*2);
  _Float16* Wq_h   = (_Float16*)alloc((size_t)512*512*2);
  _Float16* mat_h  = (_Float16*)alloc((size_t)512*1024*2);
  _Float16* mat_lo = (_Float16*)alloc((size_t)512*1024*2);
  float*    Kb     = (float*)alloc((size_t)512*512*4);
  float*    Vb     = (float*)alloc((size_t)512*512*4);
  float*    dec    = (float*)alloc((size_t)MROWS*512*4);
  float*    bsum   = (float*)alloc(2048*4);
  float*    hxA    = (float*)alloc(8*512*4);
  float*    hxB    = (float*)alloc(8*512*4);
  float*    aA     = (float*)alloc(8*512*4);
  float*    aB     = (float*)alloc(8*512*4);
  float*    rmax   = (float*)alloc(2048*4);
  float*    rsum   = (float*)alloc(2048*4);
  float*    sg     = (float*)alloc(2048*4);
  int*      bar    = (int*)alloc(256);

  auto cast = [&](const float* s, _Float16* d, int total, int sld, int soff, int dld, int doff, int cs, int lo) {
    cast_k<<<(total+255)/256, 256, 0, stream>>>(s, d, total, sld, soff, dld, doff, cs, lo);
  };
  cast(out_W,   outW_h, VOCAB*1024, 1024, 0,   1024, 0,   10, 0);
  cast(W_ih,    Wihk_h, 2048*512,   1024, 512, 512,  0,   9,  0);
  cast(W_ih,    Wc_h,   2048*512,   1024, 0,   1024, 0,   9,  0);
  cast(W_hh,    Wc_h,   2048*512,   512,  0,   1024, 512, 9,  0);
  cast(Wq,      Wq_h,   512*512,    512,  0,   512,  0,   9,  0);
  cast(Wk,      Wk_h,   512*512,    512,  0,   512,  0,   9,  0);
  cast(Wv,      Wv_h,   512*512,    512,  0,   512,  0,   9,  0);
  cast(mattn_W, mat_h,  512*1024,   1024, 0,   1024, 0,   10, 0);
  cast(mattn_W, mat_lo, 512*1024,   1024, 0,   1024, 0,   10, 1);
  cast(ents,    ents_h, 512*512,    512,  0,   512,  0,   9,  0);

  embgather_k<<<4096, 256, 0, stream>>>(emb, outp, emb_h);
  prep_k<<<16, 256, 0, stream>>>(b_ih, b_hh, ents, bsum, hxA, aA, bar);

  gemm_k<<<dim3(4,4),   256, 0, stream>>>(ents_h, Wk_h,   Kb,   nullptr, 512,  512,   512,  512,  0);
  gemm_k<<<dim3(4,4),   256, 0, stream>>>(ents_h, Wv_h,   Vb,   nullptr, 512,  512,   512,  512,  0);
  gemm_k<<<dim3(16,16), 256, 0, stream>>>(emb_h,  Wihk_h, gpre, bsum,    2048, 2048,  512,  2048, 0);

  lstm_k<<<NWG, 256, 0, stream>>>(gpre, Wc_h, Wq_h, Kb, Vb, entlens,
                                  hxA, hxB, aA, aB, l_h, l_lo, bar);

  gemm_k<<<dim3(4,16),   256, 0, stream>>>(l_h,  mat_h,  dec, mattn_b, 2048, 512,   1024, 512, 0);
  gemm_k<<<dim3(4,16),   256, 0, stream>>>(l_lo, mat_h,  dec, nullptr, 2048, 512,   1024, 512, 1);
  gemm_k<<<dim3(4,16),   256, 0, stream>>>(l_h,  mat_lo, dec, nullptr, 2048, 512,   1024, 512, 1);
  gemm_k<<<dim3(250,16), 256, 0, stream>>>(l_h,  outW_h, out, out_b,   2048, 32000, 1024, RS,  0);

  stats_k<<<2048, 256, 0, stream>>>(out, l_h, sw_W, sw_b, rmax, rsum, sg);
  fin_k<<<2048, 256, 0, stream>>>(out, dec, ents, entlens, rmax, rsum, sg);
}

// Round 2
// 8132.761 us; speedup vs baseline: 2.0689x; 2.0689x over previous
//
#include <hip/hip_runtime.h>
#include <cstdint>

#define TT 256
#define BB 8
#define NE 64
#define HH 512
#define VOCAB 32000
#define G4 2048
#define RS 32064          // out0 row stride (V + NE)
#define MROWS 2048        // B*T
#define NWG 128
#define SCALE 0.044194173824159216f  // 1/sqrt(512)

typedef _Float16 h2 __attribute__((ext_vector_type(2)));
typedef _Float16 h8 __attribute__((ext_vector_type(8)));
typedef float f4 __attribute__((ext_vector_type(4)));

__device__ inline float sigf(float x){ return 1.f/(1.f+__expf(-x)); }

// agent-scope cache-bypassing accessors (sc0 sc1 -> coherent point, no L2 maintenance)
__device__ inline float gload(const float* p){
  return __hip_atomic_load((float*)p, __ATOMIC_RELAXED, __HIP_MEMORY_SCOPE_AGENT);
}
__device__ inline void gstore(float* p, float v){
  __hip_atomic_store(p, v, __ATOMIC_RELAXED, __HIP_MEMORY_SCOPE_AGENT);
}

// ---------------- casts (f32 -> f16, hi or lo residual) ----------------
__global__ __launch_bounds__(256) void cast_k(const float* __restrict__ src, _Float16* __restrict__ dst,
    int total, int src_ld, int src_off, int dst_ld, int dst_off, int cshift, int lo)
{
  int i = blockIdx.x*256 + threadIdx.x;
  if (i >= total) return;
  int c = i & ((1<<cshift)-1);
  int r = i >> cshift;
  float x = src[(long)r*src_ld + src_off + c];
  _Float16 h = (_Float16)x;
  if (lo) h = (_Float16)(x - (float)h);
  dst[(long)r*dst_ld + dst_off + c] = h;
}

__global__ __launch_bounds__(256) void embgather_k(const float* __restrict__ emb,
    const int* __restrict__ outp, _Float16* __restrict__ dst)
{
  int i = blockIdx.x*256 + threadIdx.x;   // < 2048*512, rows m = t*8+b
  int k = i & 511; int m = i >> 9;
  int t = m >> 3, b = m & 7;
  int tok = outp[b*TT + t];
  dst[i] = (_Float16)emb[(long)tok*HH + k];
}

__global__ __launch_bounds__(256) void prep_k(const float* __restrict__ b_ih, const float* __restrict__ b_hh,
    const float* __restrict__ ents, float* bsum, float* hxA, float* aA, int* bar)
{
  int i = blockIdx.x*256 + threadIdx.x;   // grid 16 -> 4096 threads
  if (i < G4) bsum[i] = b_ih[i] + b_hh[i];
  if (i < BB*HH) {
    int b = i >> 9, j = i & 511;
    float s = 0.f;
    for (int n = 0; n < NE; n++) s += ents[(size_t)((b<<6)+n)*HH + j];
    hxA[i] = s * (1.0f/NE);   // cx0 = hx0 = mean over ALL NE entities
    aA[i]  = 0.f;
  }
  if (i < NWG) bar[i] = 0;
}

// ---------------- f16 MFMA GEMM: C[M,N](f32) = A[M,K] * B[N,K]^T (+bias) ----------------
// All of M,N,K divisible by 128/32. 128x128 tile, 4 waves each 64x64.
__global__ __launch_bounds__(256) void gemm_k(const _Float16* __restrict__ A, const _Float16* __restrict__ Bm,
    float* __restrict__ C, const float* __restrict__ bias,
    int M, int N, int K, int ldc, int accum)
{
  __shared__ __align__(16) _Float16 At[128][40];
  __shared__ __align__(16) _Float16 Bt[128][40];
  int tid = threadIdx.x;
  int n0 = blockIdx.x * 128, m0 = blockIdx.y * 128;
  int wave = tid >> 6, lane = tid & 63;
  int mw = (wave & 1) << 6, nw = (wave >> 1) << 6;
  int lr = tid >> 2, lc = (tid & 3) << 3;
  const _Float16* Ap0 = A + (long)(m0 + lr)*K + lc;
  const _Float16* Ap1 = Ap0 + (long)64*K;
  const _Float16* Bp0 = Bm + (long)(n0 + lr)*K + lc;
  const _Float16* Bp1 = Bp0 + (long)64*K;
  f4 acc[4][4] = {};
  int rr = lane & 15, kq = (lane >> 4) << 3;
  for (int kt = 0; kt < K; kt += 32) {
    h8 av0 = *(const h8*)(Ap0 + kt);
    h8 av1 = *(const h8*)(Ap1 + kt);
    h8 bv0 = *(const h8*)(Bp0 + kt);
    h8 bv1 = *(const h8*)(Bp1 + kt);
    __syncthreads();
    *(h8*)&At[lr][lc]    = av0;
    *(h8*)&At[64+lr][lc] = av1;
    *(h8*)&Bt[lr][lc]    = bv0;
    *(h8*)&Bt[64+lr][lc] = bv1;
    __syncthreads();
    h8 af[4], bf[4];
    #pragma unroll
    for (int mt=0;mt<4;mt++) af[mt] = *(const h8*)&At[mw + mt*16 + rr][kq];
    #pragma unroll
    for (int nt=0;nt<4;nt++) bf[nt] = *(const h8*)&Bt[nw + nt*16 + rr][kq];
    #pragma unroll
    for (int mt=0;mt<4;mt++)
      #pragma unroll
      for (int nt=0;nt<4;nt++)
        acc[mt][nt] = __builtin_amdgcn_mfma_f32_16x16x32_f16(af[mt], bf[nt], acc[mt][nt], 0, 0, 0);
  }
  // C/D layout: col=lane&15, row=(lane>>4)*4+reg  (dtype-independent on gfx950)
  int cc = lane & 15, rq = (lane >> 4) << 2;
  #pragma unroll
  for (int nt=0;nt<4;nt++) {
    int col = n0 + nw + nt*16 + cc;
    float bv = bias ? bias[col] : 0.f;
    #pragma unroll
    for (int mt=0;mt<4;mt++) {
      int row0 = m0 + mw + mt*16 + rq;
      #pragma unroll
      for (int r=0;r<4;r++) {
        long idx = (long)(row0 + r)*ldc + col;
        float v = acc[mt][nt][r] + bv;
        if (accum) C[idx] += v; else C[idx] = v;
      }
    }
  }
}

// ---------------- distributed-flag epoch barrier (no RMW, no fences) ----------------
// Each WG posts monotone epoch to its own slot; waiters poll one slot per lane.
// Data ordering: producers' stores are sc0sc1 (coherent-point); the
// s_waitcnt vmcnt(0) + s_barrier before the flag post guarantees they arrived.
__device__ inline void gbar2(int* bar, int wg, int target, int nslots, bool post) {
  asm volatile("s_waitcnt vmcnt(0)" ::: "memory");
  __syncthreads();
  if (post && threadIdx.x == 0)
    __hip_atomic_store(&bar[wg], target, __ATOMIC_RELAXED, __HIP_MEMORY_SCOPE_AGENT);
  if ((int)threadIdx.x < nslots) {
    while (__hip_atomic_load(&bar[threadIdx.x], __ATOMIC_RELAXED, __HIP_MEMORY_SCOPE_AGENT) < target)
      __builtin_amdgcn_s_sleep(1);
  }
  __syncthreads();
  asm volatile("" ::: "memory");
}

struct PB { float hxl[512]; float q[128]; float pr[256]; float sc2[64]; };

__global__ __launch_bounds__(256, 1) void lstm_k(
    const float* __restrict__ gates_pre, const _Float16* __restrict__ Wc,
    const _Float16* __restrict__ Wq, const float* __restrict__ Kb, const float* __restrict__ Vb,
    const int* __restrict__ entlens,
    float* hxA, float* hxB, float* aA, float* aB,
    _Float16* l_h, _Float16* l_lo, int* bar)
{
  __shared__ __align__(16) _Float16 wA[16][1032];   // 16 gate rows x 1024 (a|hx) weights
  __shared__ __align__(16) union {
    _Float16 act[8][1032];      // [b][a(512)|hx(512)]
    float red[256][17];         // padded: stride 17 breaks 16-float bank cycle
    PB pb;
  } u;
  __shared__ float cxs[32];     // persistent cell state: [b(8)][jj(4)]
  __shared__ float fin[8][16];

  int wg = blockIdx.x, tid = threadIdx.x;

  // one-time: weights -> LDS; cx init
  for (int i = tid; i < 16*1024; i += 256) {
    int rl = i >> 10, d = i & 1023;
    int gr = (rl >> 2)*512 + (wg << 2) + (rl & 3);   // gate*512 + j
    wA[rl][d] = Wc[(long)gr*1024 + d];
  }
  if (tid < 32) cxs[tid] = hxA[(tid>>2)*512 + (wg<<2) + (tid&3)];
  int el = entlens[(wg < 32) ? (wg >> 2) : 0];

  int tile = tid >> 5, ds = tid & 31;
  int bt4 = (tile >> 2) << 2;
  int rt4 = (tile & 3) << 2;
  int rb = tid >> 4, rrl = tid & 15;                  // reducer mapping (tid<128)
  int rtl = ((rb >> 2) << 2) + (rrl >> 2);
  int rai = ((rb & 3) << 2) + (rrl & 3);
  long gp_col = (long)((rrl >> 2)*512 + (wg << 2) + (rrl & 3));
  __syncthreads();

  for (int t = 0; t < TT; t++) {
    const float* hx_old = (t & 1) ? hxB : hxA;
    float*       hx_new = (t & 1) ? hxA : hxB;
    const float* a_old  = (t & 1) ? aB : aA;
    float*       a_new  = (t & 1) ? aA : aB;

    float gp = 0.f;
    if (tid < 128) gp = gates_pre[(long)((t<<3) + rb)*2048 + gp_col];

    // stage activations [a_old | hx_old] -> LDS f16 (coherent-point loads)
    for (int i = tid; i < 8192; i += 256) {
      int b = i >> 10, d = i & 1023;
      float v = (d < 512) ? gload(a_old + (b<<9) + d) : gload(hx_old + (b<<9) + d - 512);
      u.act[b][d] = (_Float16)v;
    }
    __syncthreads();

    // gates accumulation: thread tile 4b x 4rows, 32-wide d-split, f16 dot2
    float acc[4][4] = {};
    #pragma unroll
    for (int c=0;c<4;c++) {
      int d0 = ((c<<5) + ds) << 3;
      union { h8 v; h2 p[4]; } av[4], wv[4];
      #pragma unroll
      for (int i=0;i<4;i++) av[i].v = *(const h8*)&u.act[bt4+i][d0];
      #pragma unroll
      for (int i=0;i<4;i++) wv[i].v = *(const h8*)&wA[rt4+i][d0];
      #pragma unroll
      for (int bi=0;bi<4;bi++)
        #pragma unroll
        for (int ri=0;ri<4;ri++)
          #pragma unroll
          for (int p=0;p<4;p++)
            acc[bi][ri] = __builtin_amdgcn_fdot2(av[bi].p[p], wv[ri].p[p], acc[bi][ri], false);
    }
    __syncthreads();
    #pragma unroll
    for (int bi=0;bi<4;bi++)
      #pragma unroll
      for (int ri=0;ri<4;ri++)
        u.red[tid][(bi<<2)+ri] = acc[bi][ri];
    __syncthreads();
    if (tid < 128) {
      float s = gp;
      #pragma unroll 8
      for (int k=0;k<32;k++) s += u.red[(rtl<<5)+k][rai];
      fin[rb][rrl] = s;
    }
    __syncthreads();
    if (tid < 32) {                    // LSTM cell for 8b x 4j
      int b = tid >> 2, jj = tid & 3;
      float gi = fin[b][jj], gf = fin[b][4+jj], gg = fin[b][8+jj], go = fin[b][12+jj];
      float c_ = sigf(gf)*cxs[tid] + sigf(gi)*tanhf(gg);
      cxs[tid] = c_;
      float h = sigf(go)*tanhf(c_);
      int j = (wg<<2) + jj;
      gstore(hx_new + (b<<9) + j, h);
      _Float16 hh = (_Float16)h;
      long li = ((long)((b<<8) + t)) << 10;
      l_h[li + j]  = hh;
      l_lo[li + j] = (_Float16)(h - (float)hh);
    }
    gbar2(bar, wg, 2*t+1, NWG, true);

    // attention: WG w<32 owns (b = w>>2, head = w&3)
    if (wg < 32) {
      int b = wg >> 2, hid = wg & 3;
      for (int i = tid; i < 512; i += 256) u.pb.hxl[i] = gload(hx_new + (b<<9) + i);
      __syncthreads();
      {
        int qd = tid >> 1, hf = tid & 1;
        const _Float16* wq = Wq + (long)(hid*128 + qd)*512 + (hf<<8);
        const float* hp = u.pb.hxl + (hf<<8);
        float s = 0.f;
        for (int k=0;k<256;k+=8) {
          h8 wv8 = *(const h8*)(wq + k);
          #pragma unroll
          for (int j=0;j<8;j++) s += (float)wv8[j] * hp[k+j];
        }
        u.pb.pr[tid] = s;
      }
      __syncthreads();
      if (tid < 128) u.pb.q[tid] = u.pb.pr[tid<<1] + u.pb.pr[(tid<<1)+1];
      __syncthreads();
      if (tid < 64) {
        const float* kp = Kb + (long)((b<<6)+tid)*512 + hid*128;
        float s = 0.f;
        #pragma unroll 4
        for (int d=0;d<128;d+=4)
          s += u.pb.q[d]*kp[d] + u.pb.q[d+1]*kp[d+1] + u.pb.q[d+2]*kp[d+2] + u.pb.q[d+3]*kp[d+3];
        s *= SCALE;
        if (tid > el) s = -1e30f;
        float mx = s;
        #pragma unroll
        for (int off=32; off>0; off>>=1) mx = fmaxf(mx, __shfl_xor(mx, off));
        float e = __expf(s - mx);
        float sum = e;
        #pragma unroll
        for (int off=32; off>0; off>>=1) sum += __shfl_xor(sum, off);
        u.pb.sc2[tid] = e / sum;
      }
      __syncthreads();
      if (tid < 128) {
        const float* vp = Vb + ((long)(b<<6))*512 + hid*128 + tid;
        float s = 0.f;
        for (int n=0;n<NE;n++) s += u.pb.sc2[n] * vp[(long)n*512];
        gstore(a_new + (b<<9) + hid*128 + tid, s);
        _Float16 hh = (_Float16)s;
        long li = (((long)((b<<8) + t)) << 10) + 512 + hid*128 + tid;
        l_h[li]  = hh;
        l_lo[li] = (_Float16)(s - (float)hh);
      }
    }
    gbar2(bar, wg, 2*t+2, 32, wg < 32);
  }
}

// ---------------- online softmax stats over V + sigmoid switch gate ----------------
__global__ __launch_bounds__(256) void stats_k(const float* __restrict__ out0,
    const _Float16* __restrict__ l_h, const float* __restrict__ swW, const float* __restrict__ swb,
    float* rowmax, float* rowsum, float* sgate)
{
  int m = blockIdx.x, tid = threadIdx.x;
  const float* row = out0 + (long)m*RS;
  float mx = -1e30f, sm = 0.f;
  for (int c = tid; c < VOCAB; c += 256) {
    float x = row[c];
    float nm = fmaxf(mx, x);
    sm = sm*__expf(mx-nm) + __expf(x-nm);
    mx = nm;
  }
  float sd = 0.f;
  const _Float16* lr_ = l_h + ((long)m << 10);
  for (int k = tid; k < 1024; k += 256) sd += (float)lr_[k] * swW[k];
  #pragma unroll
  for (int off=32; off>0; off>>=1) {
    float omx = __shfl_xor(mx, off), osm = __shfl_xor(sm, off);
    float nm = fmaxf(mx, omx);
    sm = sm*__expf(mx-nm) + osm*__expf(omx-nm);
    mx = nm;
    sd += __shfl_xor(sd, off);
  }
  __shared__ float smx[4], ssm[4], ssd[4];
  int wv = tid >> 6;
  if ((tid & 63) == 0) { smx[wv]=mx; ssm[wv]=sm; ssd[wv]=sd; }
  __syncthreads();
  if (tid == 0) {
    float M = smx[0], S = ssm[0], D = ssd[0];
    for (int w2=1;w2<4;w2++) {
      float nm = fmaxf(M, smx[w2]);
      S = S*__expf(M-nm) + ssm[w2]*__expf(smx[w2]-nm);
      M = nm; D += ssd[w2];
    }
    rowmax[m] = M; rowsum[m] = S;
    sgate[m] = 1.f/(1.f + __expf(-(D + swb[0])));
  }
}

// ---------------- finalize: log(softmax*s + 1e-6) over V, pointer softmax z over NE ----------------
__global__ __launch_bounds__(256) void fin_k(float* __restrict__ out,
    const float* __restrict__ dec, const float* __restrict__ ents, const int* __restrict__ entlens,
    const float* __restrict__ rowmax, const float* __restrict__ rowsum, const float* __restrict__ sgate)
{
  int m = blockIdx.x, tid = threadIdx.x;
  int b = m >> 8;
  __shared__ float dl[512];
  for (int i = tid; i < 512; i += 256) dl[i] = dec[((long)m<<9) + i];
  __syncthreads();
  float s = sgate[m];
  if (tid < 64) {
    int n = tid;
    const float* ep = ents + (((long)((b<<6)+n)) << 9);
    float uq = 0.f;
    for (int k=0;k<512;k+=4)
      uq += dl[k]*ep[k] + dl[k+1]*ep[k+1] + dl[k+2]*ep[k+2] + dl[k+3]*ep[k+3];
    if (n > entlens[b]) uq = -1e30f;
    float mx = uq;
    #pragma unroll
    for (int off=32; off>0; off>>=1) mx = fmaxf(mx, __shfl_xor(mx, off));
    float e = __expf(uq - mx);
    float sum = e;
    #pragma unroll
    for (int off=32; off>0; off>>=1) sum += __shfl_xor(sum, off);
    float z = (e/sum) * (1.f - s);
    out[(long)m*RS + VOCAB + n] = __logf(z + 1e-6f);
    out[(long)MROWS*RS + ((long)m<<6) + n] = z;     // output 1
  }
  float mx = rowmax[m], inv = 1.f/rowsum[m];
  for (int c = tid; c < VOCAB; c += 256) {
    long idx = (long)m*RS + c;
    float x = out[idx];
    out[idx] = __logf(__expf(x - mx)*inv*s + 1e-6f);
  }
}

// ---------------- launch ----------------
extern "C" void kernel_launch(void* const* d_in, const int* in_sizes, int n_in,
                              void* d_out, int out_size, void* d_ws, size_t ws_size,
                              hipStream_t stream)
{
  const int*   outp    = (const int*)d_in[0];
  const float* ents    = (const float*)d_in[1];
  const int*   entlens = (const int*)d_in[2];
  const float* emb     = (const float*)d_in[3];
  const float* W_ih    = (const float*)d_in[4];
  const float* W_hh    = (const float*)d_in[5];
  const float* b_ih    = (const float*)d_in[6];
  const float* b_hh    = (const float*)d_in[7];
  const float* Wq      = (const float*)d_in[8];
  const float* Wk      = (const float*)d_in[9];
  const float* Wv      = (const float*)d_in[10];
  const float* out_W   = (const float*)d_in[11];
  const float* out_b   = (const float*)d_in[12];
  const float* sw_W    = (const float*)d_in[13];
  const float* sw_b    = (const float*)d_in[14];
  const float* mattn_W = (const float*)d_in[15];
  const float* mattn_b = (const float*)d_in[16];
  float* out = (float*)d_out;
  (void)in_sizes; (void)n_in; (void)out_size; (void)ws_size;

  char* w = (char*)d_ws;
  size_t off = 0;
  auto alloc = [&](size_t bytes) -> char* {
    char* p = w + off; off += bytes; off = (off + 255) & ~(size_t)255; return p;
  };
  // ~108 MB total workspace
  _Float16* outW_h = (_Float16*)alloc((size_t)VOCAB*1024*2);
  _Float16* l_h    = (_Float16*)alloc((size_t)MROWS*1024*2);
  _Float16* l_lo   = (_Float16*)alloc((size_t)MROWS*1024*2);
  float*    gpre   = (float*)alloc((size_t)MROWS*2048*4);
  _Float16* Wc_h   = (_Float16*)alloc((size_t)2048*1024*2);
  _Float16* Wihk_h = (_Float16*)alloc((size_t)2048*512*2);
  _Float16* emb_h  = (_Float16*)alloc((size_t)2048*512*2);
  _Float16* ents_h = (_Float16*)alloc((size_t)512*512*2);
  _Float16* Wk_h   = (_Float16*)alloc((size_t)512*512*2);
  _Float16* Wv_h   = (_Float16*)alloc((size_t)512*512*2);
  _Float16* Wq_h   = (_Float16*)alloc((size_t)512*512*2);
  _Float16* mat_h  = (_Float16*)alloc((size_t)512*1024*2);
  _Float16* mat_lo = (_Float16*)alloc((size_t)512*1024*2);
  float*    Kb     = (float*)alloc((size_t)512*512*4);
  float*    Vb     = (float*)alloc((size_t)512*512*4);
  float*    dec    = (float*)alloc((size_t)MROWS*512*4);
  float*    bsum   = (float*)alloc(2048*4);
  float*    hxA    = (float*)alloc(8*512*4);
  float*    hxB    = (float*)alloc(8*512*4);
  float*    aA     = (float*)alloc(8*512*4);
  float*    aB     = (float*)alloc(8*512*4);
  float*    rmax   = (float*)alloc(2048*4);
  float*    rsum   = (float*)alloc(2048*4);
  float*    sg     = (float*)alloc(2048*4);
  int*      bar    = (int*)alloc(1024);

  auto cast = [&](const float* s, _Float16* d, int total, int sld, int soff, int dld, int doff, int cs, int lo) {
    cast_k<<<(total+255)/256, 256, 0, stream>>>(s, d, total, sld, soff, dld, doff, cs, lo);
  };
  cast(out_W,   outW_h, VOCAB*1024, 1024, 0,   1024, 0,   10, 0);
  cast(W_ih,    Wihk_h, 2048*512,   1024, 512, 512,  0,   9,  0);
  cast(W_ih,    Wc_h,   2048*512,   1024, 0,   1024, 0,   9,  0);
  cast(W_hh,    Wc_h,   2048*512,   512,  0,   1024, 512, 9,  0);
  cast(Wq,      Wq_h,   512*512,    512,  0,   512,  0,   9,  0);
  cast(Wk,      Wk_h,   512*512,    512,  0,   512,  0,   9,  0);
  cast(Wv,      Wv_h,   512*512,    512,  0,   512,  0,   9,  0);
  cast(mattn_W, mat_h,  512*1024,   1024, 0,   1024, 0,   10, 0);
  cast(mattn_W, mat_lo, 512*1024,   1024, 0,   1024, 0,   10, 1);
  cast(ents,    ents_h, 512*512,    512,  0,   512,  0,   9,  0);

  embgather_k<<<4096, 256, 0, stream>>>(emb, outp, emb_h);
  prep_k<<<16, 256, 0, stream>>>(b_ih, b_hh, ents, bsum, hxA, aA, bar);

  gemm_k<<<dim3(4,4),   256, 0, stream>>>(ents_h, Wk_h,   Kb,   nullptr, 512,  512,   512,  512,  0);
  gemm_k<<<dim3(4,4),   256, 0, stream>>>(ents_h, Wv_h,   Vb,   nullptr, 512,  512,   512,  512,  0);
  gemm_k<<<dim3(16,16), 256, 0, stream>>>(emb_h,  Wihk_h, gpre, bsum,    2048, 2048,  512,  2048, 0);

  lstm_k<<<NWG, 256, 0, stream>>>(gpre, Wc_h, Wq_h, Kb, Vb, entlens,
                                  hxA, hxB, aA, aB, l_h, l_lo, bar);

  gemm_k<<<dim3(4,16),   256, 0, stream>>>(l_h,  mat_h,  dec, mattn_b, 2048, 512,   1024, 512, 0);
  gemm_k<<<dim3(4,16),   256, 0, stream>>>(l_lo, mat_h,  dec, nullptr, 2048, 512,   1024, 512, 1);
  gemm_k<<<dim3(4,16),   256, 0, stream>>>(l_h,  mat_lo, dec, nullptr, 2048, 512,   1024, 512, 1);
  gemm_k<<<dim3(250,16), 256, 0, stream>>>(l_h,  outW_h, out, out_b,   2048, 32000, 1024, RS,  0);

  stats_k<<<2048, 256, 0, stream>>>(out, l_h, sw_W, sw_b, rmax, rsum, sg);
  fin_k<<<2048, 256, 0, stream>>>(out, dec, ents, entlens, rmax, rsum, sg);
}